// Round 5
// baseline (303.860 us; speedup 1.0000x reference)
//
#include <hip/hip_runtime.h>
#include <stdint.h>

// BinarizeConv2dSDP: out = conv3x3(sign(x), sign(M), pad=1) * Alpha[o]
// R9: T4 counted-vmcnt pipeline (m218 lever) on top of R8:
//   - Al TRIPLE-buffered; stage issued 2 steps ahead.
//   - raw s_barrier + asm "s_waitcnt vmcnt(5)" per step instead of
//     __syncthreads (which drains vmcnt(0) and exposes stage latency).
//     Per-wave VMEM order/step: [12 wf, 5 glds16 stage(t+2)]; stage(t+1)
//     is older than all of them => vmcnt(5) proves it done. Oldest-first
//     drain makes this robust to compiler interleaving.
//   - sched_barrier(0) fences around each barrier (rule #18), setprio(1)
//     around the MFMA cluster (T5).
//   R8 kept: wave-contiguous wpk fragments, XOR-swizzled Al staging with
//   conflict-free ds_read_b128, XCD-bijective block swizzle.
// binarize_act unchanged (verified absmax 0.0).

typedef __attribute__((ext_vector_type(16))) float floatx16;
typedef __attribute__((ext_vector_type(8)))  int   intx8;

#define N_IMG 32
#define C_IN  256
#define O_OUT 256
#define HP 58
#define WP 58
#define GPI 3136                                    // 56*56 px per image
#define APAD_POS ((size_t)N_IMG * HP * WP)          // 107648 padded positions
#define APAD_BYTES (APAD_POS * C_IN)                // 27.6 MB fp8
#define TPI 13
#define AL_GRAN 1072
#define AL_BYTES (AL_GRAN * 16)                     // 17152 B per buffer
#define WPK_STEP 49152                              // 3 kw * 8 oblk * 2048 B

__device__ __forceinline__ unsigned int sgn8(float x) {
    // fp8 e4m3fn: +1.0 = 0x38, -1.0 = 0xB8, 0 = 0x00
    return x > 0.f ? 0x38u : (x < 0.f ? 0xB8u : 0u);
}

__device__ __forceinline__ void glds16(const unsigned char* g, unsigned char* l) {
    __builtin_amdgcn_global_load_lds(
        (const __attribute__((address_space(1))) unsigned int*)g,
        (__attribute__((address_space(3))) unsigned int*)l, 16, 0, 0);
}

// ---------------------------------------------------------------------------
// Binarize x (NCHW fp32) -> zero-padded NHWC fp8 sign buffer. (unchanged)
__global__ __launch_bounds__(256) void binarize_act(
    const float* __restrict__ x, unsigned char* __restrict__ apad)
{
    int bid = blockIdx.x;
    int n = bid / HP;
    int hp = bid - n * HP;
    int tid = threadIdx.x;

    unsigned char* rowp = apad + ((size_t)(n * HP + hp) * WP) * C_IN;
    uint4 z = {0u, 0u, 0u, 0u};

    if (hp == 0 || hp == HP - 1) {                    // border rows: zero 58x256B
#pragma unroll
        for (int j = 0; j < 4; ++j) {
            int t = tid + 256 * j;                    // < 928 = 58*16
            if (t < WP * 16) {
                int w = t >> 4, g = t & 15;
                *(uint4*)(rowp + (size_t)w * C_IN + g * 16) = z;
            }
        }
        return;
    }
    int h = hp - 1;

    __shared__ unsigned int tile[C_IN * 15];          // [ci][word0..13], stride 15
    __shared__ unsigned int lds2[56 * 65];            // [w][cq0..63], stride 65

    const float* xb = x + ((size_t)n * C_IN) * GPI + h * 56;
#pragma unroll
    for (int j = 0; j < 14; ++j) {                    // 256 ch x 14 float4
        int t = tid + 256 * j;
        int ci = t / 14;
        int w4 = t - ci * 14;
        float4 v = *(const float4*)(xb + (size_t)ci * GPI + w4 * 4);
        tile[ci * 15 + w4] = sgn8(v.x) | (sgn8(v.y) << 8) |
                             (sgn8(v.z) << 16) | (sgn8(v.w) << 24);
    }
    __syncthreads();

    // Phase 2a: t = whi*256 + cq*4 + wlo ; w = whi*4+wlo ; cq = channel quad
#pragma unroll
    for (int j = 0; j < 14; ++j) {
        int t = tid + 256 * j;                        // < 3584 = 14*64*4
        int wlo = t & 3;
        int cq  = (t >> 2) & 63;
        int whi = t >> 8;
        int sh = wlo * 8;
        unsigned int r = 0;
#pragma unroll
        for (int i = 0; i < 4; ++i) {
            unsigned int v = tile[(cq * 4 + i) * 15 + whi];
            r |= ((v >> sh) & 0xFFu) << (8 * i);
        }
        lds2[(whi * 4 + wlo) * 65 + cq] = r;
    }
    __syncthreads();

    // Phase 2b: 56 w x 16 uint4 -> contiguous stores (pos w+1, c = g*16..)
#pragma unroll
    for (int j = 0; j < 4; ++j) {
        int t = tid + 256 * j;                        // < 896 = 56*16
        if (t < 896) {
            int w = t >> 4, g = t & 15;
            uint4 v;
            v.x = lds2[w * 65 + g * 4 + 0];
            v.y = lds2[w * 65 + g * 4 + 1];
            v.z = lds2[w * 65 + g * 4 + 2];
            v.w = lds2[w * 65 + g * 4 + 3];
            *(uint4*)(rowp + (size_t)(w + 1) * C_IN + g * 16) = v;
        }
    }
    if (tid < 32) {                                   // zero pad cols 0 and 57
        int g = tid & 15;
        int col = (tid >> 4) * (WP - 1);
        *(uint4*)(rowp + (size_t)col * C_IN + g * 16) = z;
    }
}

// ---------------------------------------------------------------------------
// M (O,C,3,3) fp32 -> wpk fragments: [kh*4+c0q][kw][oblk] 2KB blocks laid out
// in GEMM lane order: byte (hb,u,b) at hb*1024 + (o&31)*32 + (c&31), where
// channel c = c0 + 32*hb + 16*u + b  (linear within the 64-ch window).
__global__ __launch_bounds__(64) void pack_w(
    const float* __restrict__ M, unsigned char* __restrict__ wpk)
{
    int gid = blockIdx.x * 64 + threadIdx.x;          // 16384 = 256 blk x 64
    int o = gid >> 6;
    int c4 = (gid & 63) << 2;
    const float* mb = M + (size_t)(o * C_IN + c4) * 9;
    int oblk = o >> 5;
    int c0q = c4 >> 6;
    int dst_in = ((c4 >> 5) & 1) * 1024 + (o & 31) * 32 + (c4 & 31);
#pragma unroll
    for (int t = 0; t < 9; ++t) {
        int kh = t / 3, kw = t - 3 * (t / 3);
        unsigned int r = sgn8(mb[t]) | (sgn8(mb[9 + t]) << 8) |
                         (sgn8(mb[18 + t]) << 16) | (sgn8(mb[27 + t]) << 24);
        size_t frag = (size_t)(kh * 4 + c0q) * WPK_STEP +
                      (size_t)(kw * 8 + oblk) * 2048;
        *(unsigned int*)(wpk + frag + dst_in) = r;
    }
}

// ---------------------------------------------------------------------------
__device__ __forceinline__ void stage_A(const unsigned char* __restrict__ apad,
    unsigned char* lbase, int Q0, int t, const int* al_pos, const int* al_sl,
    int wv)
{
    const int kh = t >> 2, c0 = (t & 3) << 6;
    const int rowbase = Q0 + kh * WP;
    const int plim = (int)APAD_POS - 1 - rowbase;
    const unsigned char* asrc = apad + (((size_t)rowbase << 8) + c0);
#pragma unroll
    for (int it = 0; it < 5; ++it) {
        int p = al_pos[it] < plim ? al_pos[it] : plim;
        int dst = (it < 4) ? ((it << 8) + (wv << 6)) : (816 + (wv << 6));
        glds16(asrc + ((size_t)p << 8) + al_sl[it], lbase + ((size_t)dst << 4));
    }
}

// ---------------------------------------------------------------------------
// Implicit GEMM, MX-scaled fp8 32x32x64 MFMA, counted-vmcnt 3-deep pipeline.
__global__ __launch_bounds__(256, 2) void bconv_gemm(
    const unsigned char* __restrict__ apad,
    const unsigned char* __restrict__ wpk,
    const float* __restrict__ alpha,
    float* __restrict__ out)
{
    __shared__ __align__(16) unsigned char Al[3][AL_BYTES];  // 3 x 17.15 KB

    const int tid = threadIdx.x;
    const int wv = tid >> 6, lane = tid & 63;
    const int l31 = lane & 31, hb = lane >> 5;

    // XCD-bijective swizzle: grid 832 = 8 * 104
    const int hw = blockIdx.x;
    const int bid = (hw & 7) * 104 + (hw >> 3);

    const int img = bid / 26;
    const int rem = bid - img * 26;
    const int tl = rem >> 1, ot = rem & 1;
    const int g0 = tl << 8;
    const int h0 = g0 / 56, w0 = g0 - h0 * 56;
    const int o_base = ot << 7;
    const int Q0 = (img * HP + h0) * WP + w0;

    // staging tables: gran s -> row pos = s>>2, sub gI = s&3;
    // SOURCE chunk = gI ^ ((pos>>1)&3)  (XOR swizzle on global side; LDS linear)
    int al_pos[5], al_sl[5];
#pragma unroll
    for (int it = 0; it < 5; ++it) {
        int s = (it < 4) ? (tid + (it << 8)) : (tid + 816);
        int pos = s >> 2, gI = s & 3;
        al_pos[it] = pos;
        al_sl[it]  = ((gI ^ ((pos >> 1) & 3)) << 4);
    }

    const int o_half  = (wv >> 1) << 6;
    const int px_half = (wv & 1) << 7;
    const int oblk0   = (ot << 2) + ((wv >> 1) << 1);   // + mt -> global o>>5

    int pos_tab[4], pxg[4];
#pragma unroll
    for (int nt = 0; nt < 4; ++nt) {
        int px = px_half + (nt << 5) + l31;
        pxg[nt] = g0 + px;
        int pxc = (pxg[nt] < GPI) ? px : (GPI - 1 - g0);
        pos_tab[nt] = pxc + 2 * ((w0 + pxc) / 56);
    }

    floatx16 acc[2][4] = {};

    unsigned char* Ab = &Al[0][0];

    // ---- prologue: stage steps 0 and 1
    stage_A(apad, Ab,            Q0, 0, al_pos, al_sl, wv);
    stage_A(apad, Ab + AL_BYTES, Q0, 1, al_pos, al_sl, wv);
    asm volatile("s_waitcnt vmcnt(5)" ::: "memory");   // step-0 stage done
    __builtin_amdgcn_sched_barrier(0);
    __builtin_amdgcn_s_barrier();
    __builtin_amdgcn_sched_barrier(0);

    int bc = 0;                                        // consume-buffer index
    for (int t = 0; t < 12; ++t) {                     // t = kh*4 + c0q
        // ---- W fragments for THIS step: 12 dwordx4, wave-contiguous 1KB/instr
        union WF { uint4 q[2]; intx8 v; };
        WF wf[2][3];
        {
            const unsigned char* wb = wpk + (size_t)t * WPK_STEP + ((size_t)lane << 5);
#pragma unroll
            for (int mt = 0; mt < 2; ++mt)
#pragma unroll
                for (int kw = 0; kw < 3; ++kw) {
                    const unsigned char* p = wb + (size_t)((kw << 3) + oblk0 + mt) * 2048;
                    wf[mt][kw].q[0] = *(const uint4*)(p);
                    wf[mt][kw].q[1] = *(const uint4*)(p + 16);
                }
        }

        // ---- stage step t+2 (lands by the barrier at END of step t+1)
        if (t < 10) {
            int b2 = bc + 2; if (b2 >= 3) b2 -= 3;
            stage_A(apad, Ab + b2 * AL_BYTES, Q0, t + 2, al_pos, al_sl, wv);
        }

        // ---- compute from Al[bc] + wf regs
        const unsigned char* AlC = Ab + bc * AL_BYTES;
        __builtin_amdgcn_s_setprio(1);
#pragma unroll
        for (int kw = 0; kw < 3; ++kw) {
#pragma unroll
            for (int nt = 0; nt < 4; ++nt) {
                int pos = pos_tab[nt] + kw;
                int rb = pos << 6;
                int m3 = (pos >> 1) & 3;
                union F { uint4 q[2]; intx8 v; } bf;
                bf.q[0] = *(const uint4*)&AlC[rb + ((((hb << 1))     ^ m3) << 4)];
                bf.q[1] = *(const uint4*)&AlC[rb + ((((hb << 1) | 1) ^ m3) << 4)];
#pragma unroll
                for (int mt = 0; mt < 2; ++mt)
                    acc[mt][nt] = __builtin_amdgcn_mfma_scale_f32_32x32x64_f8f6f4(
                        wf[mt][kw].v, bf.v, acc[mt][nt],
                        0, 0,                      // cbsz=fp8(e4m3), blgp=fp8(e4m3)
                        0, 0x7F7F7F7F,             // opsel_a, scale_a = 1.0
                        0, 0x7F7F7F7F);            // opsel_b, scale_b = 1.0
            }
        }
        __builtin_amdgcn_s_setprio(0);

        // ---- counted-vmcnt barrier: only stage(t+1) (oldest in flight) must
        //      be done; the <=5 still outstanding are stage(t+2).
        if (t < 11) {
            asm volatile("s_waitcnt vmcnt(5)" ::: "memory");
            __builtin_amdgcn_sched_barrier(0);
            __builtin_amdgcn_s_barrier();
            __builtin_amdgcn_sched_barrier(0);
        }
        bc = (bc + 1 == 3) ? 0 : bc + 1;
    }

#pragma unroll
    for (int mt = 0; mt < 2; ++mt) {
#pragma unroll
        for (int r = 0; r < 16; ++r) {
            int o_loc = o_half + (mt << 5) + (r & 3) + ((r >> 2) << 3) + (hb << 2);
            int o_g = o_base + o_loc;
            float a = alpha[o_g];
            float* ob = out + ((size_t)(img * O_OUT + o_g)) * GPI;
#pragma unroll
            for (int nt = 0; nt < 4; ++nt) {
                if (pxg[nt] < GPI) ob[pxg[nt]] = acc[mt][nt][r] * a;
            }
        }
    }
}

// ---------------------------------------------------------------------------
extern "C" void kernel_launch(void* const* d_in, const int* in_sizes, int n_in,
                              void* d_out, int out_size, void* d_ws, size_t ws_size,
                              hipStream_t stream) {
    const float* x     = (const float*)d_in[0];
    const float* M     = (const float*)d_in[1];
    const float* alpha = (const float*)d_in[2];
    float* out = (float*)d_out;

    unsigned char* apad = (unsigned char*)d_ws;
    unsigned char* wpk  = apad + APAD_BYTES;

    binarize_act<<<dim3(N_IMG * HP), dim3(256), 0, stream>>>(x, apad);
    pack_w<<<dim3(256), dim3(64), 0, stream>>>(M, wpk);
    bconv_gemm<<<dim3(N_IMG * TPI * 2), dim3(256), 0, stream>>>(apad, wpk, alpha, out);
}

// Round 6
// 263.535 us; speedup vs baseline: 1.1530x; 1.1530x over previous
//
#include <hip/hip_runtime.h>
#include <stdint.h>

// BinarizeConv2dSDP: out = conv3x3(sign(x), sign(M), pad=1) * Alpha[o]
// R10: revert to R6's verified-best control flow (single Al/Wl LDS buffers,
//      glds16 staging for BOTH operands, 2 __syncthreads per K-step, MX-scaled
//      fp8 32x32x64 MFMA), keeping only the measured-good R7/R8 deltas:
//   - XCD-bijective block swizzle (FETCH 61->34 MB in R7/R8).
//   - XOR chunk-swizzle on BOTH A and W staging SOURCE addresses (LDS dest
//     linear, rule #21) + paired ds_read_b128 reads: 32 lanes spread all 32
//     banks (R8 measured conflicts 1.47e7 -> 4.6e6 on the A side).
//   - pack_w re-laid out to [t][kw][o][c] 64B rows; linear channel map on
//     both operands (byte j <-> channel c0+32*hb+j) => symmetric placement,
//     bit-identical result (same argument verified absmax 0.0 in R6/R8).
// binarize_act unchanged (verified absmax 0.0).

typedef __attribute__((ext_vector_type(16))) float floatx16;
typedef __attribute__((ext_vector_type(8)))  int   intx8;

#define N_IMG 32
#define C_IN  256
#define O_OUT 256
#define HP 58
#define WP 58
#define GPI 3136                                    // 56*56 px per image
#define APAD_POS ((size_t)N_IMG * HP * WP)          // 107648 padded positions
#define APAD_BYTES (APAD_POS * C_IN)                // 27.6 MB fp8
#define TPI 13
#define AL_GRAN 1072
#define WL_GRAN 1536
#define WPK_STEP 49152                              // 3 kw * 128... = 3*16384 B

__device__ __forceinline__ unsigned int sgn8(float x) {
    // fp8 e4m3fn: +1.0 = 0x38, -1.0 = 0xB8, 0 = 0x00
    return x > 0.f ? 0x38u : (x < 0.f ? 0xB8u : 0u);
}

__device__ __forceinline__ void glds16(const unsigned char* g, unsigned char* l) {
    __builtin_amdgcn_global_load_lds(
        (const __attribute__((address_space(1))) unsigned int*)g,
        (__attribute__((address_space(3))) unsigned int*)l, 16, 0, 0);
}

// ---------------------------------------------------------------------------
// Binarize x (NCHW fp32) -> zero-padded NHWC fp8 sign buffer. (unchanged)
__global__ __launch_bounds__(256) void binarize_act(
    const float* __restrict__ x, unsigned char* __restrict__ apad)
{
    int bid = blockIdx.x;
    int n = bid / HP;
    int hp = bid - n * HP;
    int tid = threadIdx.x;

    unsigned char* rowp = apad + ((size_t)(n * HP + hp) * WP) * C_IN;
    uint4 z = {0u, 0u, 0u, 0u};

    if (hp == 0 || hp == HP - 1) {                    // border rows: zero 58x256B
#pragma unroll
        for (int j = 0; j < 4; ++j) {
            int t = tid + 256 * j;                    // < 928 = 58*16
            if (t < WP * 16) {
                int w = t >> 4, g = t & 15;
                *(uint4*)(rowp + (size_t)w * C_IN + g * 16) = z;
            }
        }
        return;
    }
    int h = hp - 1;

    __shared__ unsigned int tile[C_IN * 15];          // [ci][word0..13], stride 15
    __shared__ unsigned int lds2[56 * 65];            // [w][cq0..63], stride 65

    const float* xb = x + ((size_t)n * C_IN) * GPI + h * 56;
#pragma unroll
    for (int j = 0; j < 14; ++j) {                    // 256 ch x 14 float4
        int t = tid + 256 * j;
        int ci = t / 14;
        int w4 = t - ci * 14;
        float4 v = *(const float4*)(xb + (size_t)ci * GPI + w4 * 4);
        tile[ci * 15 + w4] = sgn8(v.x) | (sgn8(v.y) << 8) |
                             (sgn8(v.z) << 16) | (sgn8(v.w) << 24);
    }
    __syncthreads();

    // Phase 2a: t = whi*256 + cq*4 + wlo ; w = whi*4+wlo ; cq = channel quad
#pragma unroll
    for (int j = 0; j < 14; ++j) {
        int t = tid + 256 * j;                        // < 3584 = 14*64*4
        int wlo = t & 3;
        int cq  = (t >> 2) & 63;
        int whi = t >> 8;
        int sh = wlo * 8;
        unsigned int r = 0;
#pragma unroll
        for (int i = 0; i < 4; ++i) {
            unsigned int v = tile[(cq * 4 + i) * 15 + whi];
            r |= ((v >> sh) & 0xFFu) << (8 * i);
        }
        lds2[(whi * 4 + wlo) * 65 + cq] = r;
    }
    __syncthreads();

    // Phase 2b: 56 w x 16 uint4 -> contiguous stores (pos w+1, c = g*16..)
#pragma unroll
    for (int j = 0; j < 4; ++j) {
        int t = tid + 256 * j;                        // < 896 = 56*16
        if (t < 896) {
            int w = t >> 4, g = t & 15;
            uint4 v;
            v.x = lds2[w * 65 + g * 4 + 0];
            v.y = lds2[w * 65 + g * 4 + 1];
            v.z = lds2[w * 65 + g * 4 + 2];
            v.w = lds2[w * 65 + g * 4 + 3];
            *(uint4*)(rowp + (size_t)(w + 1) * C_IN + g * 16) = v;
        }
    }
    if (tid < 32) {                                   // zero pad cols 0 and 57
        int g = tid & 15;
        int col = (tid >> 4) * (WP - 1);
        *(uint4*)(rowp + (size_t)col * C_IN + g * 16) = z;
    }
}

// ---------------------------------------------------------------------------
// M (O,C,3,3) fp32 -> wpk [t=kh*4+c0q][kw][o=0..255][c=0..63] fp8 sign.
// Linear channel map: byte c63 of row (t,kw,o) = channel (t&3)*64 + c63.
__global__ __launch_bounds__(64) void pack_w(
    const float* __restrict__ M, unsigned char* __restrict__ wpk)
{
    int gid = blockIdx.x * 64 + threadIdx.x;          // 16384 = 256 blk x 64
    int o = gid >> 6;
    int c4 = (gid & 63) << 2;
    int c0q = c4 >> 6;                                // 0 here (c4<64) -- general
    int c63 = c4 & 63;
    const float* mb = M + (size_t)(o * C_IN + c4) * 9;
#pragma unroll
    for (int t = 0; t < 9; ++t) {
        int kh = t / 3, kw = t - 3 * (t / 3);
        unsigned int r = sgn8(mb[t]) | (sgn8(mb[9 + t]) << 8) |
                         (sgn8(mb[18 + t]) << 16) | (sgn8(mb[27 + t]) << 24);
        size_t dst = ((size_t)(kh * 4 + c0q) * 3 + kw) * 16384 + o * 64 + c63;
        *(unsigned int*)(wpk + dst) = r;
    }
}

// ---------------------------------------------------------------------------
// Implicit GEMM, MX-scaled fp8 32x32x64 MFMA, R6 schedule + swizzles.
__global__ __launch_bounds__(256, 2) void bconv_gemm(
    const unsigned char* __restrict__ apad,
    const unsigned char* __restrict__ wpk,
    const float* __restrict__ alpha,
    float* __restrict__ out)
{
    __shared__ __align__(16) unsigned char Al[AL_GRAN * 16];   // 16.75 KB
    __shared__ __align__(16) unsigned char Wl[WL_GRAN * 16];   // 24 KB

    const int tid = threadIdx.x;
    const int wv = tid >> 6, lane = tid & 63;
    const int l31 = lane & 31, hb = lane >> 5;

    // XCD-bijective swizzle: grid 832 = 8 * 104
    const int hw = blockIdx.x;
    const int bid = (hw & 7) * 104 + (hw >> 3);

    const int img = bid / 26;
    const int rem = bid - img * 26;
    const int tl = rem >> 1, ot = rem & 1;
    const int g0 = tl << 8;
    const int h0 = g0 / 56, w0 = g0 - h0 * 56;
    const int o_base = ot << 7;
    const int Q0 = (img * HP + h0) * WP + w0;

    // A staging: gran s -> row pos = s>>2, chunk gI = s&3;
    // SOURCE chunk = gI ^ ((pos>>1)&3)  (XOR on global side; LDS dest linear)
    int al_pos[5], al_sl[5];
#pragma unroll
    for (int it = 0; it < 5; ++it) {
        int s = (it < 4) ? (tid + (it << 8)) : (tid + 816);
        int pos = s >> 2, gI = s & 3;
        al_pos[it] = pos;
        al_sl[it]  = ((gI ^ ((pos >> 1) & 3)) << 4);
    }
    // W staging: gran s -> row r = s>>2 (kw = r>>7, o local = r&127), chunk q
    int wl_src[6];
#pragma unroll
    for (int it = 0; it < 6; ++it) {
        int s = tid + (it << 8);                      // < 1536
        int r = s >> 2, q = s & 3;
        int kw = r >> 7, ol = r & 127;
        wl_src[it] = kw * 16384 + (o_base + ol) * 64 + ((q ^ ((r >> 1) & 3)) << 4);
    }

    const int o_half  = (wv >> 1) << 6;
    const int px_half = (wv & 1) << 7;

    int pos_tab[4], pxg[4];
#pragma unroll
    for (int nt = 0; nt < 4; ++nt) {
        int px = px_half + (nt << 5) + l31;
        pxg[nt] = g0 + px;
        int pxc = (pxg[nt] < GPI) ? px : (GPI - 1 - g0);
        pos_tab[nt] = pxc + 2 * ((w0 + pxc) / 56);
    }

    floatx16 acc[2][4] = {};

    for (int t = 0; t < 12; ++t) {                    // t = kh*4 + c0q
        const int kh = t >> 2, c0 = (t & 3) << 6;
        const int rowbase = Q0 + kh * WP;
        const int plim = (int)APAD_POS - 1 - rowbase;
        const unsigned char* asrc = apad + (((size_t)rowbase << 8) + c0);
        const unsigned char* wsrc = wpk + (size_t)t * WPK_STEP;

        __syncthreads();                              // WAR: prev compute done
#pragma unroll
        for (int it = 0; it < 5; ++it) {
            int p = al_pos[it] < plim ? al_pos[it] : plim;
            int dst = (it < 4) ? ((it << 8) + (wv << 6)) : (816 + (wv << 6));
            glds16(asrc + ((size_t)p << 8) + al_sl[it], &Al[(size_t)dst << 4]);
        }
#pragma unroll
        for (int it = 0; it < 6; ++it)
            glds16(wsrc + wl_src[it], &Wl[(size_t)(tid + (it << 8)) << 4]);
        __syncthreads();                              // stage complete

        // ---- compute: K=64 per kw via one MX MFMA
#pragma unroll
        for (int kw = 0; kw < 3; ++kw) {
            union F { uint4 q[2]; intx8 v; };
            F af[2];
#pragma unroll
            for (int mt = 0; mt < 2; ++mt) {
                int rl = (kw << 7) + o_half + (mt << 5) + l31;
                int m3 = (rl >> 1) & 3;
                af[mt].q[0] = *(const uint4*)&Wl[(size_t)(rl << 6) + ((((hb << 1))     ^ m3) << 4)];
                af[mt].q[1] = *(const uint4*)&Wl[(size_t)(rl << 6) + ((((hb << 1) | 1) ^ m3) << 4)];
            }
#pragma unroll
            for (int nt = 0; nt < 4; ++nt) {
                int pos = pos_tab[nt] + kw;
                int rb = pos << 6;
                int m3 = (pos >> 1) & 3;
                F bf;
                bf.q[0] = *(const uint4*)&Al[rb + ((((hb << 1))     ^ m3) << 4)];
                bf.q[1] = *(const uint4*)&Al[rb + ((((hb << 1) | 1) ^ m3) << 4)];
#pragma unroll
                for (int mt = 0; mt < 2; ++mt)
                    acc[mt][nt] = __builtin_amdgcn_mfma_scale_f32_32x32x64_f8f6f4(
                        af[mt].v, bf.v, acc[mt][nt],
                        0, 0,                      // cbsz=fp8(e4m3), blgp=fp8(e4m3)
                        0, 0x7F7F7F7F,             // opsel_a, scale_a = 1.0
                        0, 0x7F7F7F7F);            // opsel_b, scale_b = 1.0
            }
        }
    }

#pragma unroll
    for (int mt = 0; mt < 2; ++mt) {
#pragma unroll
        for (int r = 0; r < 16; ++r) {
            int o_loc = o_half + (mt << 5) + (r & 3) + ((r >> 2) << 3) + (hb << 2);
            int o_g = o_base + o_loc;
            float a = alpha[o_g];
            float* ob = out + ((size_t)(img * O_OUT + o_g)) * GPI;
#pragma unroll
            for (int nt = 0; nt < 4; ++nt) {
                if (pxg[nt] < GPI) ob[pxg[nt]] = acc[mt][nt][r] * a;
            }
        }
    }
}

// ---------------------------------------------------------------------------
extern "C" void kernel_launch(void* const* d_in, const int* in_sizes, int n_in,
                              void* d_out, int out_size, void* d_ws, size_t ws_size,
                              hipStream_t stream) {
    const float* x     = (const float*)d_in[0];
    const float* M     = (const float*)d_in[1];
    const float* alpha = (const float*)d_in[2];
    float* out = (float*)d_out;

    unsigned char* apad = (unsigned char*)d_ws;
    unsigned char* wpk  = apad + APAD_BYTES;

    binarize_act<<<dim3(N_IMG * HP), dim3(256), 0, stream>>>(x, apad);
    pack_w<<<dim3(256), dim3(64), 0, stream>>>(M, wpk);
    bconv_gemm<<<dim3(N_IMG * TPI * 2), dim3(256), 0, stream>>>(apad, wpk, alpha, out);
}

// Round 7
// 243.165 us; speedup vs baseline: 1.2496x; 1.0838x over previous
//
#include <hip/hip_runtime.h>
#include <stdint.h>

// BinarizeConv2dSDP: out = conv3x3(sign(x), sign(M), pad=1) * Alpha[o]
// R11: fp4 (e2m1) operands on the same MX-scaled 32x32x64 f8f6f4 MFMA
//      (cbsz=blgp=4, unit scales). +/-1 is exact in e2m1 (0x2/0xA).
//   - 2x MFMA rate (m59: 9099 vs 4686 TF) AND 16B/lane operands:
//     ds_read per step 36 -> 18 b128; staging bytes and apad halve.
//   - Symmetric nibble->channel placement on A and B (byte b of chunk hb =
//     channels c0+32hb+2b, +2b+1) => any HW k-permutation cancels; same
//     argument verified absmax 0.0 for the fp8 switch (R6).
//   - LDS chunk interleave L = 2*pos + (chunk ^ ((pos>>2)&1)) applied on the
//     glds16 SOURCE (LDS dest linear): L&7 uniform over 64 lanes => reads at
//     structural bank minimum.
//   - R10 schedule kept exactly (single Al/Wl buffers, 2 barriers/step,
//     XCD-bijective swizzle).
//   binarize_act phases 1/2a unchanged; 2b adds nibble-compress (128B rows).

typedef __attribute__((ext_vector_type(16))) float floatx16;
typedef __attribute__((ext_vector_type(8)))  int   intx8;

#define N_IMG 32
#define C_IN  256
#define O_OUT 256
#define HP 58
#define WP 58
#define GPI 3136                                    // 56*56 px per image
#define APAD_POS ((size_t)N_IMG * HP * WP)          // 107648 padded positions
#define ROWB 128                                    // 256 ch x fp4 = 128 B/pos
#define APAD_BYTES (APAD_POS * ROWB)                // 13.78 MB
#define TPI 13
#define AL_CHUNKS 536                               // 268 pos x 2 x 16B
#define WL_CHUNKS 768                               // 384 rows x 2 x 16B
#define WROW 8192                                   // 256 o x 32 B
#define WPK_STEP (3 * WROW)

__device__ __forceinline__ unsigned int sgn4(float x) {
    // fp4 e2m1: +1.0 = 0x2, -1.0 = 0xA, 0 = 0x0
    return x > 0.f ? 0x2u : (x < 0.f ? 0xAu : 0u);
}

__device__ __forceinline__ void glds16(const unsigned char* g, unsigned char* l) {
    __builtin_amdgcn_global_load_lds(
        (const __attribute__((address_space(1))) unsigned int*)g,
        (__attribute__((address_space(3))) unsigned int*)l, 16, 0, 0);
}

// nibble-compress: two u32 of sign-BYTES (values 0x2/0xA/0x0) -> one u32 of
// sign-NIBBLES, byte b = ch(2b) | ch(2b+1)<<4 (channel order = byte order in).
__device__ __forceinline__ unsigned int nib16(unsigned int w) {
    return (w & 0xFu) | ((w >> 4) & 0xF0u) |
           ((w >> 8) & 0xF00u) | ((w >> 12) & 0xF000u);
}
__device__ __forceinline__ unsigned int nibc(unsigned int lo, unsigned int hi) {
    return nib16(lo) | (nib16(hi) << 16);
}

// ---------------------------------------------------------------------------
// Binarize x (NCHW fp32) -> zero-padded NHWC fp4-nibble sign buffer.
// Phases 1/2a identical to the verified R5 structure (sign value now 0x2/0xA).
__global__ __launch_bounds__(256) void binarize_act(
    const float* __restrict__ x, unsigned char* __restrict__ apad)
{
    int bid = blockIdx.x;
    int n = bid / HP;
    int hp = bid - n * HP;
    int tid = threadIdx.x;

    unsigned char* rowp = apad + (size_t)(n * HP + hp) * WP * ROWB;
    uint4 z = {0u, 0u, 0u, 0u};

    if (hp == 0 || hp == HP - 1) {                    // border rows: zero 58x128B
#pragma unroll
        for (int j = 0; j < 2; ++j) {
            int t = tid + 256 * j;                    // < 464 = 58*8
            if (t < WP * 8) {
                int w = t >> 3, g = t & 7;
                *(uint4*)(rowp + (size_t)w * ROWB + g * 16) = z;
            }
        }
        return;
    }
    int h = hp - 1;

    __shared__ unsigned int tile[C_IN * 15];          // [ci][word0..13], stride 15
    __shared__ unsigned int lds2[56 * 65];            // [w][cq0..63], stride 65

    const float* xb = x + ((size_t)n * C_IN) * GPI + h * 56;
#pragma unroll
    for (int j = 0; j < 14; ++j) {                    // 256 ch x 14 float4
        int t = tid + 256 * j;
        int ci = t / 14;
        int w4 = t - ci * 14;
        float4 v = *(const float4*)(xb + (size_t)ci * GPI + w4 * 4);
        tile[ci * 15 + w4] = sgn4(v.x) | (sgn4(v.y) << 8) |
                             (sgn4(v.z) << 16) | (sgn4(v.w) << 24);
    }
    __syncthreads();

    // Phase 2a: t = whi*256 + cq*4 + wlo ; w = whi*4+wlo ; cq = channel quad
#pragma unroll
    for (int j = 0; j < 14; ++j) {
        int t = tid + 256 * j;                        // < 3584 = 14*64*4
        int wlo = t & 3;
        int cq  = (t >> 2) & 63;
        int whi = t >> 8;
        int sh = wlo * 8;
        unsigned int r = 0;
#pragma unroll
        for (int i = 0; i < 4; ++i) {
            unsigned int v = tile[(cq * 4 + i) * 15 + whi];
            r |= ((v >> sh) & 0xFFu) << (8 * i);
        }
        lds2[(whi * 4 + wlo) * 65 + cq] = r;
    }
    __syncthreads();

    // Phase 2b: 56 w x 8 chunks(16B): 8 u32 sign-bytes -> 4 u32 nibbles.
#pragma unroll
    for (int j = 0; j < 2; ++j) {
        int t = tid + 256 * j;                        // < 448 = 56*8
        if (t < 448) {
            int w = t >> 3, g = t & 7;
            uint4 a = *(uint4*)&lds2[w * 65 + g * 8];
            uint4 b = *(uint4*)&lds2[w * 65 + g * 8 + 4];
            uint4 v;
            v.x = nibc(a.x, a.y);
            v.y = nibc(a.z, a.w);
            v.z = nibc(b.x, b.y);
            v.w = nibc(b.z, b.w);
            *(uint4*)(rowp + (size_t)(w + 1) * ROWB + g * 16) = v;
        }
    }
    if (tid < 16) {                                   // zero pad cols 0 and 57
        int g = tid & 7;
        int col = (tid >> 3) * (WP - 1);
        *(uint4*)(rowp + (size_t)col * ROWB + g * 16) = z;
    }
}

// ---------------------------------------------------------------------------
// M (O,C,3,3) fp32 -> wpk [t=kh*4+c0q][kw][o][32B] fp4 rows.
// byte b of row = channels 64*(t&3)+2b (lo nibble), +2b+1 (hi) — identical
// placement to the A side => symmetric => exact.
__global__ __launch_bounds__(64) void pack_w(
    const float* __restrict__ M, unsigned char* __restrict__ wpk)
{
    int gid = blockIdx.x * 64 + threadIdx.x;          // 16384 = 256 blk x 64
    int o = gid >> 6;
    int c4 = (gid & 63) << 2;
    int c0q = c4 >> 6;                                // which 64-ch window
    int half = (c4 & 63) >> 1;                        // byte offset in 32B row
    const float* mb = M + (size_t)(o * C_IN + c4) * 9;
#pragma unroll
    for (int t = 0; t < 9; ++t) {
        int kh = t / 3, kw = t - 3 * (t / 3);
        unsigned int r = sgn4(mb[t]) | (sgn4(mb[9 + t]) << 4) |
                         (sgn4(mb[18 + t]) << 8) | (sgn4(mb[27 + t]) << 12);
        size_t dst = (size_t)((kh * 4 + c0q) * 3 + kw) * WROW + o * 32 + half;
        *(unsigned short*)(wpk + dst) = (unsigned short)r;
    }
}

// ---------------------------------------------------------------------------
// Implicit GEMM, MX-scaled fp4 32x32x64 MFMA, R10 schedule.
__global__ __launch_bounds__(256, 2) void bconv_gemm(
    const unsigned char* __restrict__ apad,
    const unsigned char* __restrict__ wpk,
    const float* __restrict__ alpha,
    float* __restrict__ out)
{
    __shared__ __align__(16) unsigned char Al[AL_CHUNKS * 16];   // 8.6 KB
    __shared__ __align__(16) unsigned char Wl[WL_CHUNKS * 16];   // 12 KB

    const int tid = threadIdx.x;
    const int wv = tid >> 6, lane = tid & 63;
    const int l31 = lane & 31, hb = lane >> 5;

    // XCD-bijective swizzle: grid 832 = 8 * 104
    const int hw = blockIdx.x;
    const int bid = (hw & 7) * 104 + (hw >> 3);

    const int img = bid / 26;
    const int rem = bid - img * 26;
    const int tl = rem >> 1, ot = rem & 1;
    const int g0 = tl << 8;
    const int h0 = g0 / 56, w0 = g0 - h0 * 56;
    const int o_base = ot << 7;
    const int Q0 = (img * HP + h0) * WP + w0;

    // A staging: gran g -> pos = g>>1; SOURCE chunk = (g&1) ^ ((pos>>2)&1)
    // (interleave on global side; LDS dest linear in g — rule #21)
    int al_pos[3], al_co[3], al_dst[3], al_on[3];
#pragma unroll
    for (int it = 0; it < 3; ++it) {
        int g = (it < 2) ? (tid + (it << 8)) : (512 + tid);
        al_on[it] = (it < 2) || (tid < AL_CHUNKS - 512);
        int pos = g >> 1;
        al_pos[it] = pos;
        al_co[it]  = (((g & 1) ^ ((pos >> 2) & 1)) << 4);
        al_dst[it] = g << 4;
    }
    // W staging: gran g -> row r = g>>1 (kw = r>>7, o local = r&127)
    int wl_src[3], wl_dst[3];
#pragma unroll
    for (int it = 0; it < 3; ++it) {
        int g = tid + (it << 8);                      // < 768
        int r = g >> 1, q = (g & 1) ^ ((r >> 2) & 1);
        int kw = r >> 7, ol = r & 127;
        wl_src[it] = kw * WROW + (o_base + ol) * 32 + (q << 4);
        wl_dst[it] = g << 4;
    }

    const int o_half  = (wv >> 1) << 6;
    const int px_half = (wv & 1) << 7;

    int pos_tab[4], pxg[4];
#pragma unroll
    for (int nt = 0; nt < 4; ++nt) {
        int px = px_half + (nt << 5) + l31;
        pxg[nt] = g0 + px;
        int pxc = (pxg[nt] < GPI) ? px : (GPI - 1 - g0);
        pos_tab[nt] = pxc + 2 * ((w0 + pxc) / 56);
    }

    floatx16 acc[2][4] = {};
    const uint4 z4 = {0u, 0u, 0u, 0u};

    for (int t = 0; t < 12; ++t) {                    // t = kh*4 + c0q
        const int kh = t >> 2;
        const int cb0 = (t & 3) << 5;                 // byte offset of 64-ch window
        const int rowbase = Q0 + kh * WP;
        const int plim = (int)APAD_POS - 1 - rowbase;
        const unsigned char* asrc = apad + ((size_t)rowbase * ROWB + cb0);
        const unsigned char* wsrc = wpk + (size_t)t * WPK_STEP;

        __syncthreads();                              // WAR: prev compute done
#pragma unroll
        for (int it = 0; it < 3; ++it) {
            if (al_on[it]) {
                int p = al_pos[it] < plim ? al_pos[it] : plim;
                glds16(asrc + (size_t)p * ROWB + al_co[it], &Al[al_dst[it]]);
            }
        }
#pragma unroll
        for (int it = 0; it < 3; ++it)
            glds16(wsrc + wl_src[it], &Wl[wl_dst[it]]);
        __syncthreads();                              // stage complete

        // ---- compute: K=64 per kw via one fp4 MX MFMA
#pragma unroll
        for (int kw = 0; kw < 3; ++kw) {
            union F { uint4 q[2]; intx8 v; };
            F af[2];
#pragma unroll
            for (int mt = 0; mt < 2; ++mt) {
                int rl = (kw << 7) + o_half + (mt << 5) + l31;
                int L = (rl << 1) + (hb ^ ((rl >> 2) & 1));
                af[mt].q[0] = *(const uint4*)&Wl[(size_t)L << 4];
                af[mt].q[1] = z4;
            }
#pragma unroll
            for (int nt = 0; nt < 4; ++nt) {
                int pos = pos_tab[nt] + kw;
                int L = (pos << 1) + (hb ^ ((pos >> 2) & 1));
                F bf;
                bf.q[0] = *(const uint4*)&Al[(size_t)L << 4];
                bf.q[1] = z4;
#pragma unroll
                for (int mt = 0; mt < 2; ++mt)
                    acc[mt][nt] = __builtin_amdgcn_mfma_scale_f32_32x32x64_f8f6f4(
                        af[mt].v, bf.v, acc[mt][nt],
                        4, 4,                      // cbsz=fp4(e2m1), blgp=fp4(e2m1)
                        0, 0x7F7F7F7F,             // opsel_a, scale_a = 1.0
                        0, 0x7F7F7F7F);            // opsel_b, scale_b = 1.0
            }
        }
    }

#pragma unroll
    for (int mt = 0; mt < 2; ++mt) {
#pragma unroll
        for (int r = 0; r < 16; ++r) {
            int o_loc = o_half + (mt << 5) + (r & 3) + ((r >> 2) << 3) + (hb << 2);
            int o_g = o_base + o_loc;
            float a = alpha[o_g];
            float* ob = out + ((size_t)(img * O_OUT + o_g)) * GPI;
#pragma unroll
            for (int nt = 0; nt < 4; ++nt) {
                if (pxg[nt] < GPI) ob[pxg[nt]] = acc[mt][nt][r] * a;
            }
        }
    }
}

// ---------------------------------------------------------------------------
extern "C" void kernel_launch(void* const* d_in, const int* in_sizes, int n_in,
                              void* d_out, int out_size, void* d_ws, size_t ws_size,
                              hipStream_t stream) {
    const float* x     = (const float*)d_in[0];
    const float* M     = (const float*)d_in[1];
    const float* alpha = (const float*)d_in[2];
    float* out = (float*)d_out;

    unsigned char* apad = (unsigned char*)d_ws;
    unsigned char* wpk  = apad + APAD_BYTES;

    binarize_act<<<dim3(N_IMG * HP), dim3(256), 0, stream>>>(x, apad);
    pack_w<<<dim3(256), dim3(64), 0, stream>>>(M, wpk);
    bconv_gemm<<<dim3(N_IMG * TPI * 2), dim3(256), 0, stream>>>(apad, wpk, alpha, out);
}